// Round 1
// baseline (839.496 us; speedup 1.0000x reference)
//
#include <hip/hip_runtime.h>

#define N_BINS 15

// Row layout: C = 128 floats = 512 B. Half-wave (32 lanes) per row, float4 per lane.
__global__ __launch_bounds__(256) void ece_main(const float* __restrict__ logits,
                                                const int* __restrict__ labels,
                                                float* __restrict__ ws, // [3*N_BINS]
                                                int N) {
    __shared__ float s_counts[N_BINS];
    __shared__ float s_conf[N_BINS];
    __shared__ float s_acc[N_BINS];
    const int tid = threadIdx.x;
    if (tid < N_BINS) { s_counts[tid] = 0.f; s_conf[tid] = 0.f; s_acc[tid] = 0.f; }
    __syncthreads();

    const int lane        = tid & 63;
    const int half        = lane >> 5;   // which half-wave (row slot)
    const int sub         = lane & 31;   // lane within the 32-lane half
    const int waveInBlock = tid >> 6;    // 0..3
    const int rowsPerBlk  = (blockDim.x >> 6) * 2;  // 8 rows per block iteration

    const int rowBase   = blockIdx.x * rowsPerBlk + waveInBlock * 2 + half;
    const int rowStride = gridDim.x * rowsPerBlk;

    for (int row = rowBase; row < N; row += rowStride) {
        const float4* p = (const float4*)(logits + (size_t)row * 128) + sub;
        const float4 v = *p;

        // local max + argmax (first-max tie-break like jnp.argmax)
        float m = v.x; int mi = sub * 4;
        if (v.y > m) { m = v.y; mi = sub * 4 + 1; }
        if (v.z > m) { m = v.z; mi = sub * 4 + 2; }
        if (v.w > m) { m = v.w; mi = sub * 4 + 3; }

        // 32-lane xor-reduction (offsets < 32 never cross the half boundary on wave64)
        #pragma unroll
        for (int off = 16; off > 0; off >>= 1) {
            float om = __shfl_xor(m, off);
            int   oi = __shfl_xor(mi, off);
            if (om > m || (om == m && oi < mi)) { m = om; mi = oi; }
        }

        float s = __expf(v.x - m) + __expf(v.y - m) + __expf(v.z - m) + __expf(v.w - m);
        #pragma unroll
        for (int off = 16; off > 0; off >>= 1)
            s += __shfl_xor(s, off);

        if (sub == 0) {
            const float conf = 1.0f / s;                 // exp(m-m)/sum
            int bin = (int)ceilf(conf * (float)N_BINS) - 1;
            bin = min(max(bin, 0), N_BINS - 1);
            const float acc = (mi == labels[row]) ? 1.0f : 0.0f;
            atomicAdd(&s_counts[bin], 1.0f);
            atomicAdd(&s_conf[bin],  conf);
            atomicAdd(&s_acc[bin],   acc);
        }
    }
    __syncthreads();
    if (tid < N_BINS) {
        atomicAdd(&ws[tid],              s_counts[tid]);
        atomicAdd(&ws[N_BINS + tid],     s_conf[tid]);
        atomicAdd(&ws[2 * N_BINS + tid], s_acc[tid]);
    }
}

__global__ void ece_final(const float* __restrict__ ws, float* __restrict__ out, float invN) {
    if (threadIdx.x == 0 && blockIdx.x == 0) {
        float ece = 0.f;
        #pragma unroll
        for (int i = 0; i < N_BINS; ++i) {
            const float c = ws[i];
            if (c > 0.f)
                ece += fabsf(ws[N_BINS + i] - ws[2 * N_BINS + i]) * invN;
        }
        out[0] = ece;
    }
}

extern "C" void kernel_launch(void* const* d_in, const int* in_sizes, int n_in,
                              void* d_out, int out_size, void* d_ws, size_t ws_size,
                              hipStream_t stream) {
    const float* logits = (const float*)d_in[0];
    const int*   labels = (const int*)d_in[1];
    float*       out    = (float*)d_out;
    float*       ws     = (float*)d_ws;

    const int N = in_sizes[1];            // 1048576 rows (C fixed at 128)

    hipMemsetAsync(ws, 0, 3 * N_BINS * sizeof(float), stream);

    const int block = 256;
    const int rowsPerBlk = (block >> 6) * 2;           // 8
    int grid = 8192;                                   // grid-stride; 32 blocks/CU queued
    if ((size_t)grid * rowsPerBlk > (size_t)N)
        grid = (N + rowsPerBlk - 1) / rowsPerBlk;

    ece_main<<<grid, block, 0, stream>>>(logits, labels, ws, N);
    ece_final<<<1, 64, 0, stream>>>(ws, out, 1.0f / (float)N);
}

// Round 2
// 719.902 us; speedup vs baseline: 1.1661x; 1.1661x over previous
//
#include <hip/hip_runtime.h>

#define N_BINS 15
#define GRID_MAIN 2048
#define BLOCK 256

// C = 128 floats = 512 B/row. Half-wave (32 lanes) owns 2 rows per iteration,
// float4 per lane per row -> each wave64 streams 2 KiB contiguous per iter.
__global__ __launch_bounds__(BLOCK) void ece_main(const float* __restrict__ logits,
                                                  const int* __restrict__ labels,
                                                  float* __restrict__ partial, // [3*N_BINS * nBlocks]
                                                  int N, int nBlocks) {
    __shared__ float s_acc[3 * N_BINS];
    const int tid = threadIdx.x;
    if (tid < 3 * N_BINS) s_acc[tid] = 0.f;
    __syncthreads();

    const int hw  = tid >> 5;   // half-wave id in block: 0..7
    const int sub = tid & 31;   // lane within half-wave

    auto process = [&](const float4 v, int row) {
        // local max + argmax (first-max tie-break, matching jnp.argmax)
        float m = v.x; int mi = sub * 4;
        if (v.y > m) { m = v.y; mi = sub * 4 + 1; }
        if (v.z > m) { m = v.z; mi = sub * 4 + 2; }
        if (v.w > m) { m = v.w; mi = sub * 4 + 3; }
        #pragma unroll
        for (int off = 16; off > 0; off >>= 1) {   // stays within the 32-lane half on wave64
            float om = __shfl_xor(m, off);
            int   oi = __shfl_xor(mi, off);
            if (om > m || (om == m && oi < mi)) { m = om; mi = oi; }
        }
        float s = __expf(v.x - m) + __expf(v.y - m) + __expf(v.z - m) + __expf(v.w - m);
        #pragma unroll
        for (int off = 16; off > 0; off >>= 1)
            s += __shfl_xor(s, off);
        if (sub == 0) {
            const float conf = 1.0f / s;           // exp(m-m)/sum = max prob
            int bin = (int)ceilf(conf * (float)N_BINS) - 1;
            bin = min(max(bin, 0), N_BINS - 1);
            const float acc = (mi == labels[row]) ? 1.0f : 0.0f;
            atomicAdd(&s_acc[bin],              1.0f);
            atomicAdd(&s_acc[N_BINS + bin],     conf);
            atomicAdd(&s_acc[2 * N_BINS + bin], acc);
        }
    };

    const int rowsPerIter = (BLOCK >> 5) * 2;      // 16 rows per block-iteration
    const int rowStride   = nBlocks * rowsPerIter;

    for (int base = blockIdx.x * rowsPerIter + hw * 2; base < N; base += rowStride) {
        const int r0 = base, r1 = base + 1;
        const float4 v0 = ((const float4*)(logits + (size_t)r0 * 128))[sub];
        float4 v1;
        const bool has1 = (r1 < N);
        if (has1) v1 = ((const float4*)(logits + (size_t)r1 * 128))[sub];
        process(v0, r0);
        if (has1) process(v1, r1);
    }

    __syncthreads();
    // Per-block partial store: every slot written, no init / no global atomics needed.
    if (tid < 3 * N_BINS)
        partial[(size_t)tid * nBlocks + blockIdx.x] = s_acc[tid];
}

__global__ __launch_bounds__(1024) void ece_final(const float* __restrict__ partial,
                                                  float* __restrict__ out,
                                                  int nBlocks, float invN) {
    __shared__ float red[3 * N_BINS];
    const int tid = threadIdx.x;
    const int w = tid >> 6, lane = tid & 63;
    for (int s = w; s < 3 * N_BINS; s += 16) {     // wave w reduces slots w, w+16, w+32
        float sum = 0.f;
        for (int i = lane; i < nBlocks; i += 64)
            sum += partial[(size_t)s * nBlocks + i];
        #pragma unroll
        for (int off = 32; off > 0; off >>= 1)
            sum += __shfl_xor(sum, off);
        if (lane == 0) red[s] = sum;
    }
    __syncthreads();
    if (tid == 0) {
        float ece = 0.f;
        #pragma unroll
        for (int b = 0; b < N_BINS; ++b) {
            if (red[b] > 0.f)
                ece += fabsf(red[N_BINS + b] - red[2 * N_BINS + b]) * invN;
        }
        out[0] = ece;
    }
}

extern "C" void kernel_launch(void* const* d_in, const int* in_sizes, int n_in,
                              void* d_out, int out_size, void* d_ws, size_t ws_size,
                              hipStream_t stream) {
    const float* logits = (const float*)d_in[0];
    const int*   labels = (const int*)d_in[1];
    float*       out    = (float*)d_out;
    float*       partial = (float*)d_ws;           // 3*N_BINS*GRID_MAIN floats = 360 KB

    const int N = in_sizes[1];                     // 1048576 rows (C fixed at 128)

    int grid = GRID_MAIN;                          // 8 blocks/CU, exactly full residency
    const int rowsPerIter = (BLOCK >> 5) * 2;
    if ((size_t)grid * rowsPerIter > (size_t)N)
        grid = (N + rowsPerIter - 1) / rowsPerIter;

    ece_main<<<grid, BLOCK, 0, stream>>>(logits, labels, partial, N, grid);
    ece_final<<<1, 1024, 0, stream>>>(partial, out, grid, 1.0f / (float)N);
}

// Round 3
// 716.991 us; speedup vs baseline: 1.1709x; 1.0041x over previous
//
#include <hip/hip_runtime.h>

#define N_BINS 15
#define GRID_MAIN 2048
#define BLOCK 256
#define ROWS_PER_HW 4   // rows per half-wave per iteration (MLP unroll)

// C = 128 floats = 512 B/row. Half-wave (32 lanes) owns ROWS_PER_HW rows per
// iteration, float4 per lane per row -> 4 independent 16B loads in flight.
__global__ __launch_bounds__(BLOCK) void ece_main(const float* __restrict__ logits,
                                                  const int* __restrict__ labels,
                                                  float* __restrict__ partial, // [3*N_BINS * nBlocks]
                                                  int N, int nBlocks) {
    __shared__ float s_acc[3 * N_BINS];
    const int tid = threadIdx.x;
    if (tid < 3 * N_BINS) s_acc[tid] = 0.f;
    __syncthreads();

    const int hw  = tid >> 5;   // half-wave id in block: 0..7
    const int sub = tid & 31;   // lane within half-wave

    auto process = [&](const float4 v, int row) {
        // local max + argmax (first-max tie-break, matching jnp.argmax)
        float m = v.x; int mi = sub * 4;
        if (v.y > m) { m = v.y; mi = sub * 4 + 1; }
        if (v.z > m) { m = v.z; mi = sub * 4 + 2; }
        if (v.w > m) { m = v.w; mi = sub * 4 + 3; }
        #pragma unroll
        for (int off = 16; off > 0; off >>= 1) {   // stays within the 32-lane half on wave64
            float om = __shfl_xor(m, off);
            int   oi = __shfl_xor(mi, off);
            if (om > m || (om == m && oi < mi)) { m = om; mi = oi; }
        }
        float s = __expf(v.x - m) + __expf(v.y - m) + __expf(v.z - m) + __expf(v.w - m);
        #pragma unroll
        for (int off = 16; off > 0; off >>= 1)
            s += __shfl_xor(s, off);
        if (sub == 0) {
            const float conf = 1.0f / s;           // exp(m-m)/sum = max prob
            int bin = (int)ceilf(conf * (float)N_BINS) - 1;
            bin = min(max(bin, 0), N_BINS - 1);
            const float acc = (mi == labels[row]) ? 1.0f : 0.0f;
            atomicAdd(&s_acc[bin],              1.0f);
            atomicAdd(&s_acc[N_BINS + bin],     conf);
            atomicAdd(&s_acc[2 * N_BINS + bin], acc);
        }
    };

    const int rowsPerIter = (BLOCK >> 5) * ROWS_PER_HW;  // 32 rows per block-iteration
    const int rowStride   = nBlocks * rowsPerIter;

    for (int base = blockIdx.x * rowsPerIter + hw * ROWS_PER_HW; base < N; base += rowStride) {
        float4 v[ROWS_PER_HW];
        bool   has[ROWS_PER_HW];
        #pragma unroll
        for (int j = 0; j < ROWS_PER_HW; ++j) {
            has[j] = (base + j) < N;
            if (has[j]) v[j] = ((const float4*)(logits + (size_t)(base + j) * 128))[sub];
        }
        #pragma unroll
        for (int j = 0; j < ROWS_PER_HW; ++j)
            if (has[j]) process(v[j], base + j);
    }

    __syncthreads();
    // Per-block partial store: every slot written, no init / no global atomics needed.
    if (tid < 3 * N_BINS)
        partial[(size_t)tid * nBlocks + blockIdx.x] = s_acc[tid];
}

__global__ __launch_bounds__(1024) void ece_final(const float* __restrict__ partial,
                                                  float* __restrict__ out,
                                                  int nBlocks, float invN) {
    __shared__ float red[3 * N_BINS];
    const int tid = threadIdx.x;
    const int w = tid >> 6, lane = tid & 63;
    for (int s = w; s < 3 * N_BINS; s += 16) {     // wave w reduces slots w, w+16, w+32
        float sum = 0.f;
        for (int i = lane; i < nBlocks; i += 64)
            sum += partial[(size_t)s * nBlocks + i];
        #pragma unroll
        for (int off = 32; off > 0; off >>= 1)
            sum += __shfl_xor(sum, off);
        if (lane == 0) red[s] = sum;
    }
    __syncthreads();
    if (tid == 0) {
        float ece = 0.f;
        #pragma unroll
        for (int b = 0; b < N_BINS; ++b) {
            if (red[b] > 0.f)
                ece += fabsf(red[N_BINS + b] - red[2 * N_BINS + b]) * invN;
        }
        out[0] = ece;
    }
}

extern "C" void kernel_launch(void* const* d_in, const int* in_sizes, int n_in,
                              void* d_out, int out_size, void* d_ws, size_t ws_size,
                              hipStream_t stream) {
    const float* logits = (const float*)d_in[0];
    const int*   labels = (const int*)d_in[1];
    float*       out    = (float*)d_out;
    float*       partial = (float*)d_ws;           // 3*N_BINS*GRID_MAIN floats = 368 KB

    const int N = in_sizes[1];                     // 1048576 rows (C fixed at 128)

    int grid = GRID_MAIN;                          // 8 blocks/CU, full residency
    const int rowsPerIter = (BLOCK >> 5) * ROWS_PER_HW;
    if ((size_t)grid * rowsPerIter > (size_t)N)
        grid = (N + rowsPerIter - 1) / rowsPerIter;

    ece_main<<<grid, BLOCK, 0, stream>>>(logits, labels, partial, N, grid);
    ece_final<<<1, 1024, 0, stream>>>(partial, out, grid, 1.0f / (float)N);
}